// Round 22
// baseline (180.194 us; speedup 1.0000x reference)
//
#include <hip/hip_runtime.h>
#include <hip/hip_bf16.h>
#include <stdint.h>

// Problem constants
// B=2, S=2048, HID=2048, NH=16, NKV=4, DH=128
// QKV fused GEMM: M=4096, K=2048, N=3072 (Q:0..2047, K:2048..2559, V:2560..3071)

typedef __attribute__((ext_vector_type(8))) short short8;
typedef __attribute__((ext_vector_type(4))) float floatx4;
typedef __hip_bfloat16 bf16_t;

#define MFMA16x16(a, b, c) __builtin_amdgcn_mfma_f32_16x16x32_bf16(a, b, c, 0, 0, 0)

__device__ __forceinline__ void async_copy16(const void* g, void* l) {
  __builtin_amdgcn_global_load_lds(
      (const __attribute__((address_space(1))) void*)g,
      (__attribute__((address_space(3))) void*)l, 16, 0, 0);
}

__device__ __forceinline__ unsigned short bf16bits(float x) {
  bf16_t h = __float2bfloat16(x);
  return *reinterpret_cast<unsigned short*>(&h);
}

// hardware base-2 exponential (v_exp_f32); HIP has no __exp2f device builtin
__device__ __forceinline__ float fast_exp2(float x) {
  return __builtin_amdgcn_exp2f(x);
}

// ---------------- prep: hs f32->bf16 convert + all weight transposes ----------------
// blocks [0,8192): convbf over hs (float4 per thread).
// blocks [8192,18432): 32x32 transpose tiles: [0,4096) Wq, [4096,5120) Wk,
// [5120,6144) Wv, [6144,10240) Wo. K = 2048 for all.
__global__ __launch_bounds__(256) void prep_kernel(
    const float* __restrict__ hs, bf16_t* __restrict__ hsb,
    const float* __restrict__ Wq, const float* __restrict__ Wk,
    const float* __restrict__ Wv, const float* __restrict__ Wo,
    bf16_t* __restrict__ wqkv, bf16_t* __restrict__ wot) {
  __shared__ float t[32][33];
  const int bidx = blockIdx.x;
  if (bidx < 8192) {
    int i = bidx * 256 + threadIdx.x;
    const float4 v = reinterpret_cast<const float4*>(hs)[i];
    ushort4 o;
    o.x = bf16bits(v.x); o.y = bf16bits(v.y); o.z = bf16bits(v.z); o.w = bf16bits(v.w);
    reinterpret_cast<ushort4*>(hsb)[i] = o;
    return;
  }
  const int id = bidx - 8192;
  const int tx = threadIdx.x & 31, ty = threadIdx.x >> 5;
  const float* W;
  bf16_t* dst;
  int N, roff, tile;
  if (id < 4096)      { W = Wq; dst = wqkv; N = 2048; roff = 0;    tile = id; }
  else if (id < 5120) { W = Wk; dst = wqkv; N = 512;  roff = 2048; tile = id - 4096; }
  else if (id < 6144) { W = Wv; dst = wqkv; N = 512;  roff = 2560; tile = id - 5120; }
  else                { W = Wo; dst = wot;  N = 2048; roff = 0;    tile = id - 6144; }
  const int tilesX = N >> 5;
  const int n0 = (tile % tilesX) * 32, k0 = (tile / tilesX) * 32;
#pragma unroll
  for (int j = 0; j < 4; ++j)
    t[ty + j * 8][tx] = W[(size_t)(k0 + ty + j * 8) * N + n0 + tx];
  __syncthreads();
#pragma unroll
  for (int j = 0; j < 4; ++j) {
    int n = n0 + ty + j * 8, k = k0 + tx;
    dst[(size_t)(roff + n) * 2048 + k] = __float2bfloat16(t[tx][ty + j * 8]);
  }
}

// ---------------- GEMM: C[M][ldc] = A[M][K](bf16) x Bt[N][K](bf16)^T ----------------
// 128x128 tile, BK=64, 3 blocks/CU (natural: VGPR 96). T1 bijective XCD swizzle.
// Kept on the verified m97 structure (~930 TF): the 8-phase 256^2 rewrite needs
// derived per-phase vmcnt waits that can't be race-screened in this loop.
template <int OBF>
__global__ __launch_bounds__(256, 3) void gemm_bt_kernel(const bf16_t* __restrict__ A,
                                                         const bf16_t* __restrict__ Bt,
                                                         void* __restrict__ Cv,
                                                         int K, int ldc) {
  __shared__ __align__(16) char smem[32768];
  const int tid = threadIdx.x;
  const int wave = tid >> 6, lane = tid & 63;
  const int wr = wave >> 1, wc = wave & 1;
  const int l16 = lane & 15, lhi = lane >> 4;

  // XCD-aware remap of the flattened grid (nwg % 8 == 0 for both launches)
  const int nwg = gridDim.x * gridDim.y;
  const int orig = blockIdx.y * gridDim.x + blockIdx.x;
  const int swz = (orig & 7) * (nwg >> 3) + (orig >> 3);
  const int bn = (swz % gridDim.x) * 128;
  const int bm = (swz / gridDim.x) * 128;

  floatx4 acc[4][4] = {};

  for (int k0 = 0; k0 < K; k0 += 64) {
    __syncthreads();
#pragma unroll
    for (int i = 0; i < 4; ++i) {
      int chunk = i * 4 + wave;
      unsigned p = (unsigned)chunk * 1024u + (unsigned)lane * 16u;
      unsigned row = p >> 7;
      unsigned colg = (p & 127u) ^ ((row & 7u) << 4);
      const char* gA = (const char*)(A + (size_t)(bm + row) * K + k0) + colg;
      async_copy16(gA, smem + (size_t)chunk * 1024);
      const char* gB = (const char*)(Bt + (size_t)(bn + row) * K + k0) + colg;
      async_copy16(gB, smem + 16384 + (size_t)chunk * 1024);
    }
    __syncthreads();
#pragma unroll
    for (int kk = 0; kk < 2; ++kk) {
      short8 fa[4], fb[4];
#pragma unroll
      for (int mi = 0; mi < 4; ++mi) {
        unsigned row = wr * 64 + mi * 16 + l16;
        unsigned off = row * 128u + kk * 64u + lhi * 16u;
        off ^= (row & 7u) << 4;
        fa[mi] = *(const short8*)(smem + off);
      }
#pragma unroll
      for (int ni = 0; ni < 4; ++ni) {
        unsigned row = wc * 64 + ni * 16 + l16;
        unsigned off = row * 128u + kk * 64u + lhi * 16u;
        off ^= (row & 7u) << 4;
        fb[ni] = *(const short8*)(smem + 16384 + off);
      }
#pragma unroll
      for (int mi = 0; mi < 4; ++mi)
#pragma unroll
        for (int ni = 0; ni < 4; ++ni)
          acc[mi][ni] = MFMA16x16(fa[mi], fb[ni], acc[mi][ni]);
    }
  }
#pragma unroll
  for (int mi = 0; mi < 4; ++mi)
#pragma unroll
    for (int ni = 0; ni < 4; ++ni)
#pragma unroll
      for (int r = 0; r < 4; ++r) {
        int row = bm + wr * 64 + mi * 16 + lhi * 4 + r;
        int col = bn + wc * 64 + ni * 16 + l16;
        if (OBF)
          ((bf16_t*)Cv)[(size_t)row * ldc + col] = __float2bfloat16(acc[mi][ni][r]);
        else
          ((float*)Cv)[(size_t)row * ldc + col] = acc[mi][ni][r];
      }
}

// ---------------- post: RMSNorm+RoPE relayout (Q,K) + V transpose, one launch ------
// blocks [0,20480): qknorm tasks, VECTORIZED: lane owns elements (2l, 2l+1) as
// ushort2/float2; rotate-half partner (d <-> d+-64) is lane^32 via one shfl_xor.
// Q pre-scaled by (1/sqrt(DH))*log2(e). blocks [20480,22528): vtrans 32x32 tiles.
__global__ __launch_bounds__(256) void post_kernel(
    const bf16_t* __restrict__ Cqkv, const float* __restrict__ cosT,
    const float* __restrict__ sinT, const float* __restrict__ qw,
    const float* __restrict__ kw, bf16_t* __restrict__ Qa,
    bf16_t* __restrict__ Ka, bf16_t* __restrict__ Vt) {
  __shared__ bf16_t t[32][33];
  const int bidx = blockIdx.x;
  if (bidx < 20480) {
    int wave = threadIdx.x >> 6, lane = threadIdx.x & 63;
    int task = bidx * 4 + wave;
    int unit = task % 20;
    int row = task / 20;
    int b = row >> 11, s = row & 2047;
    const bf16_t* src;
    const float* w;
    bf16_t* dst;
    float sc;
    if (unit < 16) {
      src = Cqkv + (size_t)row * 3072 + unit * 128;
      w = qw;
      dst = Qa + ((size_t)(b * 16 + unit) * 2048 + s) * 128;
      sc = 0.127517432f;  // (1/sqrt(128)) * log2(e)
    } else {
      int kh = unit - 16;
      src = Cqkv + (size_t)row * 3072 + 2048 + kh * 128;
      w = kw;
      dst = Ka + ((size_t)(b * 4 + kh) * 2048 + s) * 128;
      sc = 1.0f;
    }
    const int d0 = lane * 2;
    ushort2 xv = *reinterpret_cast<const ushort2*>(
        reinterpret_cast<const unsigned short*>(src) + d0);
    bf16_t ba = *reinterpret_cast<bf16_t*>(&xv.x);
    bf16_t bb = *reinterpret_cast<bf16_t*>(&xv.y);
    float xa = __bfloat162float(ba), xb = __bfloat162float(bb);
    float ss = xa * xa + xb * xb;
#pragma unroll
    for (int off = 1; off < 64; off <<= 1) ss += __shfl_xor(ss, off, 64);
    float inv = rsqrtf(ss * (1.f / 128.f) + 1e-6f);
    float2 wv = *reinterpret_cast<const float2*>(w + d0);
    xa = xa * inv * wv.x;
    xb = xb * inv * wv.y;
    // rotate-half partner: lane^32 holds d^64 pair (post-norm, post-weight values)
    float pa = __shfl_xor(xa, 32, 64);
    float pb = __shfl_xor(xb, 32, 64);
    float ra = (lane < 32) ? -pa : pa;
    float rb = (lane < 32) ? -pb : pb;
    float2 cv = *reinterpret_cast<const float2*>(cosT + (size_t)s * 128 + d0);
    float2 sv = *reinterpret_cast<const float2*>(sinT + (size_t)s * 128 + d0);
    float o1 = (xa * cv.x + ra * sv.x) * sc;
    float o2 = (xb * cv.y + rb * sv.y) * sc;
    unsigned pack = (unsigned)bf16bits(o1) | ((unsigned)bf16bits(o2) << 16);
    *reinterpret_cast<unsigned*>(reinterpret_cast<unsigned short*>(dst) + d0) = pack;
    return;
  }
  // vtrans tile: decode old dim3(64,4,8) from flat id
  const int id = bidx - 20480;
  const int xs = id & 63, yd = (id >> 6) & 3, bk = id >> 8;
  const int tx = threadIdx.x & 31, ty = threadIdx.x >> 5;
  const int b = bk >> 2, kh = bk & 3;
  const int s0 = xs * 32, d0 = yd * 32;
  const bf16_t* src = Cqkv + (size_t)(b * 2048) * 3072 + 2560 + kh * 128;
#pragma unroll
  for (int j = 0; j < 4; ++j)
    t[ty + j * 8][tx] = src[(size_t)(s0 + ty + j * 8) * 3072 + d0 + tx];
  __syncthreads();
  bf16_t* dst = Vt + (size_t)(b * 4 + kh) * 128 * 2048;
#pragma unroll
  for (int j = 0; j < 4; ++j) {
    int d = d0 + ty + j * 8, s = s0 + tx;
    dst[(size_t)d * 2048 + s] = t[tx][ty + j * 8];
  }
}

// swizzle: 3-bit XOR field in bits 4-6 of the byte offset
__device__ __forceinline__ unsigned swz_row(unsigned row) {
  return (((row & 7u) ^ ((row >> 3) << 1)) & 7u) << 4;
}

// task -> qb map: 32 q-tiles of 64 rows. CU c runs tasks {t, t+8, t+16, t+24}
// (4 blocks/CU, 1024 blocks, one round); each quadruple's qb sums to 62 ->
// per-CU chunk work is constant. Heavy tiles first.
__device__ __constant__ unsigned char kQbMap[32] = {
    31, 30, 29, 28, 27, 26, 25, 24,  0, 1, 2, 3, 4, 5, 6, 7,
    23, 22, 21, 20, 19, 18, 17, 16,  8, 9, 10, 11, 12, 13, 14, 15};

// ---------------- Flash attention v10 (causal, GQA) ----------------
// QBLK=16/wave (64 rows/block, 1024 blocks, 4 blocks/CU co-resident, VGPR 68).
// In-register softmax (swapped QK^T, keymap), exp2 (log2e folded into Q scale),
// ones-column lsum MFMA, stage-after-barrier overlap, KVBLK=64, 32KB LDS.
// LDS-pipe-bound at ~90% (measured r20): structural plateau for this tiling.
__global__ __launch_bounds__(256, 2) void flash_kernel(const bf16_t* __restrict__ Qa,
                                                       const bf16_t* __restrict__ Ka,
                                                       const bf16_t* __restrict__ Vt,
                                                       bf16_t* __restrict__ attnO) {
  __shared__ __align__(16) char smem[32768];
  const int tid = threadIdx.x;
  const int wave = tid >> 6, lane = tid & 63;
  const int l16 = lane & 15, lhi = lane >> 4;
  const int bid = blockIdx.x;          // 1024 blocks
  const int bh = bid & 31;             // b*16 + h
  const int qb = kQbMap[bid >> 5];     // 0..31 (64-row q-tile)
  const int h = bh & 15, b = bh >> 4;
  const int kh = h >> 2;
  const int q0b = qb << 6;
  const int q0w = q0b + wave * 16;

  const bf16_t* Qb = Qa + ((size_t)bh * 2048 + q0w) * 128;
  const bf16_t* Kb = Ka + (size_t)(b * 4 + kh) * 2048 * 128;
  const bf16_t* Vb = Vt + (size_t)(b * 4 + kh) * 128 * 2048;

  char* Kl = smem;          // [64 keys][256B] swizzled
  char* Vl = smem + 16384;  // [128 d][128B] swizzled

  // Q fragments (B-operand): lane: q-col l16, d-slots kk*32+lhi*8+j
  short8 qf[4];
#pragma unroll
  for (int kk = 0; kk < 4; ++kk)
    qf[kk] = *(const short8*)(Qb + (size_t)l16 * 128 + kk * 32 + lhi * 8);

  short8 onesf;
#pragma unroll
  for (int j = 0; j < 8; ++j) onesf[j] = (short)0x3F80;  // bf16 1.0

  floatx4 o[8] = {};   // O rows lhi*4+r, cols f*16+l16
  floatx4 lsum = {};
  short8 pf[2];        // P A-frags per 32-key slot
  float m = -1e30f;    // per-lane running max (log2 units) for q = q0w + l16

  const float THR = 11.5f;  // = 8 nats in log2 units
  const int nch = qb + 1;

  auto stageK = [&](int key0) {
#pragma unroll
    for (int it = 0; it < 4; ++it) {
      unsigned p = (unsigned)(it * 4 + wave) * 1024u + (unsigned)lane * 16u;
      unsigned row = p >> 8;
      unsigned gcol = (p & 255u) ^ swz_row(row);
      async_copy16((const char*)(Kb + (size_t)(key0 + row) * 128) + gcol,
                   Kl + (size_t)(it * 4 + wave) * 1024);
    }
  };
  auto stageV = [&](int key0) {
#pragma unroll
    for (int it = 0; it < 4; ++it) {
      unsigned p = (unsigned)(it * 4 + wave) * 1024u + (unsigned)lane * 16u;
      unsigned row = p >> 7;
      unsigned gcol = (p & 127u) ^ swz_row(row);
      async_copy16((const char*)(Vb + (size_t)row * 2048 + key0) + gcol,
                   Vl + (size_t)(it * 4 + wave) * 1024);
    }
  };

  // prologue: stage chunk 0
  stageK(0);
  stageV(0);
  __syncthreads();

  for (int c = 0; c < nch; ++c) {
    const int kc0 = c << 6;

    // QK^T (swapped): s[g] C-layout: q-col = l16, key = kc0+lhi*8+(g&1)*4+r+(g>>1)*32
    floatx4 s[4] = {};
    __builtin_amdgcn_s_setprio(1);
#pragma unroll
    for (int g = 0; g < 4; ++g) {
      unsigned row = (unsigned)(l16 >> 2) * 8u + (unsigned)((g & 1) * 4) +
                     (unsigned)(l16 & 3) + (unsigned)((g >> 1) * 32);
      unsigned base = row * 256u;
      unsigned px = swz_row(row);
#pragma unroll
      for (int kk = 0; kk < 4; ++kk) {
        short8 kf = *(const short8*)(Kl + base + (((unsigned)(kk * 64 + lhi * 16)) ^ px));
        s[g] = MFMA16x16(kf, qf[kk], s[g]);
      }
    }
    __builtin_amdgcn_s_setprio(0);

    const int qrow = q0w + l16;
    if (kc0 + 64 > q0w) {  // mask needed only on the diagonal chunk
#pragma unroll
      for (int g = 0; g < 4; ++g)
#pragma unroll
        for (int r = 0; r < 4; ++r) {
          int key = kc0 + lhi * 8 + (g & 1) * 4 + r + (g >> 1) * 32;
          if (key > qrow) s[g][r] = -1e9f;
        }
    }
    // row max: pairwise tree over 16 in-lane values, then 2 shfl across lhi groups
    float m0 = fmaxf(fmaxf(s[0][0], s[0][1]), fmaxf(s[0][2], s[0][3]));
    float m1 = fmaxf(fmaxf(s[1][0], s[1][1]), fmaxf(s[1][2], s[1][3]));
    float m2 = fmaxf(fmaxf(s[2][0], s[2][1]), fmaxf(s[2][2], s[2][3]));
    float m3 = fmaxf(fmaxf(s[3][0], s[3][1]), fmaxf(s[3][2], s[3][3]));
    float mx = fmaxf(fmaxf(m0, m1), fmaxf(m2, m3));
    mx = fmaxf(mx, __shfl_xor(mx, 16, 64));
    mx = fmaxf(mx, __shfl_xor(mx, 32, 64));
    bool grow = mx > m + THR;
    if (__any(grow)) {
      float mn = fmaxf(m, mx);
      float corr = fast_exp2(m - mn);
      m = mn;
#pragma unroll
      for (int r = 0; r < 4; ++r) {
        float co = __shfl(corr, lhi * 4 + r, 64);  // softmax layout -> O layout
        lsum[r] *= co;
#pragma unroll
        for (int f = 0; f < 8; ++f) o[f][r] *= co;
      }
    }
    // p = exp2(s - m), pack to PV A-frags fully in-register
#pragma unroll
    for (int ks = 0; ks < 2; ++ks) {
      union { unsigned u[4]; short8 v; } pk;
#pragma unroll
      for (int half = 0; half < 2; ++half) {
        int g = ks * 2 + half;
        float p0 = fast_exp2(s[g][0] - m);
        float p1 = fast_exp2(s[g][1] - m);
        float p2 = fast_exp2(s[g][2] - m);
        float p3 = fast_exp2(s[g][3] - m);
        pk.u[half * 2] = (unsigned)bf16bits(p0) | ((unsigned)bf16bits(p1) << 16);
        pk.u[half * 2 + 1] = (unsigned)bf16bits(p2) | ((unsigned)bf16bits(p3) << 16);
      }
      pf[ks] = pk.v;
    }

    __syncthreads();  // QK done (K free), V_c staging drained

    // issue K_{c+1} staging (lands during PV)
    if (c + 1 < nch) stageK((c + 1) << 6);

    // PV + ones-column row-sum (pf in registers)
    __builtin_amdgcn_s_setprio(1);
#pragma unroll
    for (int ks = 0; ks < 2; ++ks) {
#pragma unroll
      for (int f = 0; f < 8; ++f) {
        unsigned row = (unsigned)(f * 16 + l16);
        short8 vf = *(const short8*)(Vl + row * 128u +
                                     (((unsigned)(ks * 64 + lhi * 16)) ^ swz_row(row)));
        o[f] = MFMA16x16(pf[ks], vf, o[f]);
      }
      lsum = MFMA16x16(pf[ks], onesf, lsum);
    }
    __builtin_amdgcn_s_setprio(0);

    __syncthreads();  // PV done (V free), K_{c+1} staging drained

    // issue V_{c+1} staging (lands during next QK+softmax)
    if (c + 1 < nch) stageV((c + 1) << 6);
  }

  // epilogue: O rows = q0w + lhi*4 + r, cols f*16 + l16
#pragma unroll
  for (int r = 0; r < 4; ++r) {
    float inv = 1.f / lsum[r];
    int row = q0w + lhi * 4 + r;
    size_t base = ((size_t)(b * 2048) + row) * 2048 + h * 128;
#pragma unroll
    for (int f = 0; f < 8; ++f)
      attnO[base + f * 16 + l16] = __float2bfloat16(o[f][r] * inv);
  }
}

// ---------------- launch ----------------
extern "C" void kernel_launch(void* const* d_in, const int* in_sizes, int n_in,
                              void* d_out, int out_size, void* d_ws, size_t ws_size,
                              hipStream_t stream) {
  const float* hs = (const float*)d_in[0];
  const float* cosT = (const float*)d_in[2];
  const float* sinT = (const float*)d_in[3];
  const float* Wq = (const float*)d_in[4];
  const float* Wk = (const float*)d_in[5];
  const float* Wv = (const float*)d_in[6];
  const float* Wo = (const float*)d_in[7];
  const float* qw = (const float*)d_in[8];
  const float* kw = (const float*)d_in[9];
  float* out = (float*)d_out;

  char* ws = (char*)d_ws;
  size_t off = 0;
  auto alloc = [&](size_t bytes) {
    char* p = ws + off;
    off += (bytes + 255) & ~(size_t)255;
    return p;
  };
  bf16_t* hsb  = (bf16_t*)alloc((size_t)4096 * 2048 * 2);
  bf16_t* wqkv = (bf16_t*)alloc((size_t)3072 * 2048 * 2);
  bf16_t* wot  = (bf16_t*)alloc((size_t)2048 * 2048 * 2);
  bf16_t* cqkv = (bf16_t*)alloc((size_t)4096 * 3072 * 2);  // QKV gemm out (bf16)
  bf16_t* qa   = (bf16_t*)alloc((size_t)2 * 16 * 2048 * 128 * 2);
  bf16_t* ka   = (bf16_t*)alloc((size_t)2 * 4 * 2048 * 128 * 2);
  bf16_t* vt   = (bf16_t*)alloc((size_t)2 * 4 * 2048 * 128 * 2);
  bf16_t* attn = (bf16_t*)cqkv;  // reuse (cqkv dead after relayout kernels)

  prep_kernel<<<18432, 256, 0, stream>>>(hs, hsb, Wq, Wk, Wv, Wo, wqkv, wot);
  gemm_bt_kernel<1><<<dim3(24, 32), 256, 0, stream>>>(hsb, wqkv, cqkv, 2048, 3072);
  post_kernel<<<22528, 256, 0, stream>>>(cqkv, cosT, sinT, qw, kw, qa, ka, vt);
  flash_kernel<<<1024, 256, 0, stream>>>(qa, ka, vt, attn);
  gemm_bt_kernel<0><<<dim3(16, 32), 256, 0, stream>>>(attn, wot, out, 2048, 2048);
}

// Round 23
// 179.252 us; speedup vs baseline: 1.0053x; 1.0053x over previous
//
#include <hip/hip_runtime.h>
#include <hip/hip_bf16.h>
#include <stdint.h>

// Problem constants
// B=2, S=2048, HID=2048, NH=16, NKV=4, DH=128
// QKV fused GEMM: M=4096, K=2048, N=3072 (Q:0..2047, K:2048..2559, V:2560..3071)

typedef __attribute__((ext_vector_type(8))) short short8;
typedef __attribute__((ext_vector_type(4))) float floatx4;
typedef __hip_bfloat16 bf16_t;

#define MFMA16x16(a, b, c) __builtin_amdgcn_mfma_f32_16x16x32_bf16(a, b, c, 0, 0, 0)

__device__ __forceinline__ void async_copy16(const void* g, void* l) {
  __builtin_amdgcn_global_load_lds(
      (const __attribute__((address_space(1))) void*)g,
      (__attribute__((address_space(3))) void*)l, 16, 0, 0);
}

__device__ __forceinline__ unsigned short bf16bits(float x) {
  bf16_t h = __float2bfloat16(x);
  return *reinterpret_cast<unsigned short*>(&h);
}

// hardware base-2 exponential (v_exp_f32); HIP has no __exp2f device builtin
__device__ __forceinline__ float fast_exp2(float x) {
  return __builtin_amdgcn_exp2f(x);
}

// ---------------- prep: hs f32->bf16 convert + all weight transposes ----------------
// blocks [0,8192): convbf over hs (float4 per thread).
// blocks [8192,18432): 32x32 transpose tiles: [0,4096) Wq, [4096,5120) Wk,
// [5120,6144) Wv, [6144,10240) Wo. K = 2048 for all.
__global__ __launch_bounds__(256) void prep_kernel(
    const float* __restrict__ hs, bf16_t* __restrict__ hsb,
    const float* __restrict__ Wq, const float* __restrict__ Wk,
    const float* __restrict__ Wv, const float* __restrict__ Wo,
    bf16_t* __restrict__ wqkv, bf16_t* __restrict__ wot) {
  __shared__ float t[32][33];
  const int bidx = blockIdx.x;
  if (bidx < 8192) {
    int i = bidx * 256 + threadIdx.x;
    const float4 v = reinterpret_cast<const float4*>(hs)[i];
    ushort4 o;
    o.x = bf16bits(v.x); o.y = bf16bits(v.y); o.z = bf16bits(v.z); o.w = bf16bits(v.w);
    reinterpret_cast<ushort4*>(hsb)[i] = o;
    return;
  }
  const int id = bidx - 8192;
  const int tx = threadIdx.x & 31, ty = threadIdx.x >> 5;
  const float* W;
  bf16_t* dst;
  int N, roff, tile;
  if (id < 4096)      { W = Wq; dst = wqkv; N = 2048; roff = 0;    tile = id; }
  else if (id < 5120) { W = Wk; dst = wqkv; N = 512;  roff = 2048; tile = id - 4096; }
  else if (id < 6144) { W = Wv; dst = wqkv; N = 512;  roff = 2560; tile = id - 5120; }
  else                { W = Wo; dst = wot;  N = 2048; roff = 0;    tile = id - 6144; }
  const int tilesX = N >> 5;
  const int n0 = (tile % tilesX) * 32, k0 = (tile / tilesX) * 32;
#pragma unroll
  for (int j = 0; j < 4; ++j)
    t[ty + j * 8][tx] = W[(size_t)(k0 + ty + j * 8) * N + n0 + tx];
  __syncthreads();
#pragma unroll
  for (int j = 0; j < 4; ++j) {
    int n = n0 + ty + j * 8, k = k0 + tx;
    dst[(size_t)(roff + n) * 2048 + k] = __float2bfloat16(t[tx][ty + j * 8]);
  }
}

// ---------------- GEMM: C[M][ldc] = A[M][K](bf16) x Bt[N][K](bf16)^T ----------------
// 128x128 tile, BK=64, 3 blocks/CU (natural: VGPR 96). T1 bijective XCD swizzle.
// Kept on the verified m97 structure (~930 TF): the 8-phase 256^2 rewrite needs
// derived per-phase vmcnt waits that can't be race-screened in this loop.
template <int OBF>
__global__ __launch_bounds__(256, 3) void gemm_bt_kernel(const bf16_t* __restrict__ A,
                                                         const bf16_t* __restrict__ Bt,
                                                         void* __restrict__ Cv,
                                                         int K, int ldc) {
  __shared__ __align__(16) char smem[32768];
  const int tid = threadIdx.x;
  const int wave = tid >> 6, lane = tid & 63;
  const int wr = wave >> 1, wc = wave & 1;
  const int l16 = lane & 15, lhi = lane >> 4;

  // XCD-aware remap of the flattened grid (nwg % 8 == 0 for both launches)
  const int nwg = gridDim.x * gridDim.y;
  const int orig = blockIdx.y * gridDim.x + blockIdx.x;
  const int swz = (orig & 7) * (nwg >> 3) + (orig >> 3);
  const int bn = (swz % gridDim.x) * 128;
  const int bm = (swz / gridDim.x) * 128;

  floatx4 acc[4][4] = {};

  for (int k0 = 0; k0 < K; k0 += 64) {
    __syncthreads();
#pragma unroll
    for (int i = 0; i < 4; ++i) {
      int chunk = i * 4 + wave;
      unsigned p = (unsigned)chunk * 1024u + (unsigned)lane * 16u;
      unsigned row = p >> 7;
      unsigned colg = (p & 127u) ^ ((row & 7u) << 4);
      const char* gA = (const char*)(A + (size_t)(bm + row) * K + k0) + colg;
      async_copy16(gA, smem + (size_t)chunk * 1024);
      const char* gB = (const char*)(Bt + (size_t)(bn + row) * K + k0) + colg;
      async_copy16(gB, smem + 16384 + (size_t)chunk * 1024);
    }
    __syncthreads();
#pragma unroll
    for (int kk = 0; kk < 2; ++kk) {
      short8 fa[4], fb[4];
#pragma unroll
      for (int mi = 0; mi < 4; ++mi) {
        unsigned row = wr * 64 + mi * 16 + l16;
        unsigned off = row * 128u + kk * 64u + lhi * 16u;
        off ^= (row & 7u) << 4;
        fa[mi] = *(const short8*)(smem + off);
      }
#pragma unroll
      for (int ni = 0; ni < 4; ++ni) {
        unsigned row = wc * 64 + ni * 16 + l16;
        unsigned off = row * 128u + kk * 64u + lhi * 16u;
        off ^= (row & 7u) << 4;
        fb[ni] = *(const short8*)(smem + 16384 + off);
      }
#pragma unroll
      for (int mi = 0; mi < 4; ++mi)
#pragma unroll
        for (int ni = 0; ni < 4; ++ni)
          acc[mi][ni] = MFMA16x16(fa[mi], fb[ni], acc[mi][ni]);
    }
  }
#pragma unroll
  for (int mi = 0; mi < 4; ++mi)
#pragma unroll
    for (int ni = 0; ni < 4; ++ni)
#pragma unroll
      for (int r = 0; r < 4; ++r) {
        int row = bm + wr * 64 + mi * 16 + lhi * 4 + r;
        int col = bn + wc * 64 + ni * 16 + l16;
        if (OBF)
          ((bf16_t*)Cv)[(size_t)row * ldc + col] = __float2bfloat16(acc[mi][ni][r]);
        else
          ((float*)Cv)[(size_t)row * ldc + col] = acc[mi][ni][r];
      }
}

// ---------------- post: RMSNorm+RoPE relayout (Q,K) + V transpose, one launch ------
// blocks [0,20480): qknorm tasks (wave per (row,unit)); Q pre-scaled by
// (1/sqrt(DH))*log2(e). blocks [20480,22528): vtrans 32x32 tiles.
__global__ __launch_bounds__(256) void post_kernel(
    const bf16_t* __restrict__ Cqkv, const float* __restrict__ cosT,
    const float* __restrict__ sinT, const float* __restrict__ qw,
    const float* __restrict__ kw, bf16_t* __restrict__ Qa,
    bf16_t* __restrict__ Ka, bf16_t* __restrict__ Vt) {
  __shared__ bf16_t t[32][33];
  const int bidx = blockIdx.x;
  if (bidx < 20480) {
    int wave = threadIdx.x >> 6, lane = threadIdx.x & 63;
    int task = bidx * 4 + wave;
    int unit = task % 20;
    int row = task / 20;
    int b = row >> 11, s = row & 2047;
    const bf16_t* src;
    const float* w;
    bf16_t* dst;
    float sc;
    if (unit < 16) {
      src = Cqkv + (size_t)row * 3072 + unit * 128;
      w = qw;
      dst = Qa + ((size_t)(b * 16 + unit) * 2048 + s) * 128;
      sc = 0.127517432f;  // (1/sqrt(128)) * log2(e)
    } else {
      int kh = unit - 16;
      src = Cqkv + (size_t)row * 3072 + 2048 + kh * 128;
      w = kw;
      dst = Ka + ((size_t)(b * 4 + kh) * 2048 + s) * 128;
      sc = 1.0f;
    }
    float x1 = __bfloat162float(src[lane]), x2 = __bfloat162float(src[lane + 64]);
    float ss = x1 * x1 + x2 * x2;
#pragma unroll
    for (int off = 1; off < 64; off <<= 1) ss += __shfl_xor(ss, off, 64);
    float inv = rsqrtf(ss * (1.f / 128.f) + 1e-6f);
    x1 = x1 * inv * w[lane];
    x2 = x2 * inv * w[lane + 64];
    float c1 = cosT[(size_t)s * 128 + lane], c2 = cosT[(size_t)s * 128 + lane + 64];
    float s1 = sinT[(size_t)s * 128 + lane], s2 = sinT[(size_t)s * 128 + lane + 64];
    dst[lane] = __float2bfloat16((x1 * c1 - x2 * s1) * sc);
    dst[lane + 64] = __float2bfloat16((x2 * c2 + x1 * s2) * sc);
    return;
  }
  // vtrans tile: decode old dim3(64,4,8) from flat id
  const int id = bidx - 20480;
  const int xs = id & 63, yd = (id >> 6) & 3, bk = id >> 8;
  const int tx = threadIdx.x & 31, ty = threadIdx.x >> 5;
  const int b = bk >> 2, kh = bk & 3;
  const int s0 = xs * 32, d0 = yd * 32;
  const bf16_t* src = Cqkv + (size_t)(b * 2048) * 3072 + 2560 + kh * 128;
#pragma unroll
  for (int j = 0; j < 4; ++j)
    t[ty + j * 8][tx] = src[(size_t)(s0 + ty + j * 8) * 3072 + d0 + tx];
  __syncthreads();
  bf16_t* dst = Vt + (size_t)(b * 4 + kh) * 128 * 2048;
#pragma unroll
  for (int j = 0; j < 4; ++j) {
    int d = d0 + ty + j * 8, s = s0 + tx;
    dst[(size_t)d * 2048 + s] = t[tx][ty + j * 8];
  }
}

// swizzle: 3-bit XOR field in bits 4-6 of the byte offset
__device__ __forceinline__ unsigned swz_row(unsigned row) {
  return (((row & 7u) ^ ((row >> 3) << 1)) & 7u) << 4;
}

// task -> qb map: 32 q-tiles of 64 rows. CU c runs tasks {t, t+8, t+16, t+24}
// (4 blocks/CU, 1024 blocks, one round); each quadruple's qb sums to 62 ->
// per-CU chunk work is constant. Heavy tiles first.
__device__ __constant__ unsigned char kQbMap[32] = {
    31, 30, 29, 28, 27, 26, 25, 24,  0, 1, 2, 3, 4, 5, 6, 7,
    23, 22, 21, 20, 19, 18, 17, 16,  8, 9, 10, 11, 12, 13, 14, 15};

// ---------------- Flash attention v10 (causal, GQA) ----------------
// QBLK=16/wave (64 rows/block, 1024 blocks, 4 blocks/CU co-resident, VGPR 68).
// In-register softmax (swapped QK^T, keymap), exp2 (log2e folded into Q scale),
// ones-column lsum MFMA, stage-after-barrier overlap, KVBLK=64, 32KB LDS.
// LDS-pipe-bound at ~90% (measured r20): structural plateau for this tiling.
__global__ __launch_bounds__(256, 2) void flash_kernel(const bf16_t* __restrict__ Qa,
                                                       const bf16_t* __restrict__ Ka,
                                                       const bf16_t* __restrict__ Vt,
                                                       bf16_t* __restrict__ attnO) {
  __shared__ __align__(16) char smem[32768];
  const int tid = threadIdx.x;
  const int wave = tid >> 6, lane = tid & 63;
  const int l16 = lane & 15, lhi = lane >> 4;
  const int bid = blockIdx.x;          // 1024 blocks
  const int bh = bid & 31;             // b*16 + h
  const int qb = kQbMap[bid >> 5];     // 0..31 (64-row q-tile)
  const int h = bh & 15, b = bh >> 4;
  const int kh = h >> 2;
  const int q0b = qb << 6;
  const int q0w = q0b + wave * 16;

  const bf16_t* Qb = Qa + ((size_t)bh * 2048 + q0w) * 128;
  const bf16_t* Kb = Ka + (size_t)(b * 4 + kh) * 2048 * 128;
  const bf16_t* Vb = Vt + (size_t)(b * 4 + kh) * 128 * 2048;

  char* Kl = smem;          // [64 keys][256B] swizzled
  char* Vl = smem + 16384;  // [128 d][128B] swizzled

  // Q fragments (B-operand): lane: q-col l16, d-slots kk*32+lhi*8+j
  short8 qf[4];
#pragma unroll
  for (int kk = 0; kk < 4; ++kk)
    qf[kk] = *(const short8*)(Qb + (size_t)l16 * 128 + kk * 32 + lhi * 8);

  short8 onesf;
#pragma unroll
  for (int j = 0; j < 8; ++j) onesf[j] = (short)0x3F80;  // bf16 1.0

  floatx4 o[8] = {};   // O rows lhi*4+r, cols f*16+l16
  floatx4 lsum = {};
  short8 pf[2];        // P A-frags per 32-key slot
  float m = -1e30f;    // per-lane running max (log2 units) for q = q0w + l16

  const float THR = 11.5f;  // = 8 nats in log2 units
  const int nch = qb + 1;

  auto stageK = [&](int key0) {
#pragma unroll
    for (int it = 0; it < 4; ++it) {
      unsigned p = (unsigned)(it * 4 + wave) * 1024u + (unsigned)lane * 16u;
      unsigned row = p >> 8;
      unsigned gcol = (p & 255u) ^ swz_row(row);
      async_copy16((const char*)(Kb + (size_t)(key0 + row) * 128) + gcol,
                   Kl + (size_t)(it * 4 + wave) * 1024);
    }
  };
  auto stageV = [&](int key0) {
#pragma unroll
    for (int it = 0; it < 4; ++it) {
      unsigned p = (unsigned)(it * 4 + wave) * 1024u + (unsigned)lane * 16u;
      unsigned row = p >> 7;
      unsigned gcol = (p & 127u) ^ swz_row(row);
      async_copy16((const char*)(Vb + (size_t)row * 2048 + key0) + gcol,
                   Vl + (size_t)(it * 4 + wave) * 1024);
    }
  };

  // prologue: stage chunk 0
  stageK(0);
  stageV(0);
  __syncthreads();

  for (int c = 0; c < nch; ++c) {
    const int kc0 = c << 6;

    // QK^T (swapped): s[g] C-layout: q-col = l16, key = kc0+lhi*8+(g&1)*4+r+(g>>1)*32
    floatx4 s[4] = {};
    __builtin_amdgcn_s_setprio(1);
#pragma unroll
    for (int g = 0; g < 4; ++g) {
      unsigned row = (unsigned)(l16 >> 2) * 8u + (unsigned)((g & 1) * 4) +
                     (unsigned)(l16 & 3) + (unsigned)((g >> 1) * 32);
      unsigned base = row * 256u;
      unsigned px = swz_row(row);
#pragma unroll
      for (int kk = 0; kk < 4; ++kk) {
        short8 kf = *(const short8*)(Kl + base + (((unsigned)(kk * 64 + lhi * 16)) ^ px));
        s[g] = MFMA16x16(kf, qf[kk], s[g]);
      }
    }
    __builtin_amdgcn_s_setprio(0);

    const int qrow = q0w + l16;
    if (kc0 + 64 > q0w) {  // mask needed only on the diagonal chunk
#pragma unroll
      for (int g = 0; g < 4; ++g)
#pragma unroll
        for (int r = 0; r < 4; ++r) {
          int key = kc0 + lhi * 8 + (g & 1) * 4 + r + (g >> 1) * 32;
          if (key > qrow) s[g][r] = -1e9f;
        }
    }
    // row max: pairwise tree over 16 in-lane values, then 2 shfl across lhi groups
    float m0 = fmaxf(fmaxf(s[0][0], s[0][1]), fmaxf(s[0][2], s[0][3]));
    float m1 = fmaxf(fmaxf(s[1][0], s[1][1]), fmaxf(s[1][2], s[1][3]));
    float m2 = fmaxf(fmaxf(s[2][0], s[2][1]), fmaxf(s[2][2], s[2][3]));
    float m3 = fmaxf(fmaxf(s[3][0], s[3][1]), fmaxf(s[3][2], s[3][3]));
    float mx = fmaxf(fmaxf(m0, m1), fmaxf(m2, m3));
    mx = fmaxf(mx, __shfl_xor(mx, 16, 64));
    mx = fmaxf(mx, __shfl_xor(mx, 32, 64));
    bool grow = mx > m + THR;
    if (__any(grow)) {
      float mn = fmaxf(m, mx);
      float corr = fast_exp2(m - mn);
      m = mn;
#pragma unroll
      for (int r = 0; r < 4; ++r) {
        float co = __shfl(corr, lhi * 4 + r, 64);  // softmax layout -> O layout
        lsum[r] *= co;
#pragma unroll
        for (int f = 0; f < 8; ++f) o[f][r] *= co;
      }
    }
    // p = exp2(s - m), pack to PV A-frags fully in-register
#pragma unroll
    for (int ks = 0; ks < 2; ++ks) {
      union { unsigned u[4]; short8 v; } pk;
#pragma unroll
      for (int half = 0; half < 2; ++half) {
        int g = ks * 2 + half;
        float p0 = fast_exp2(s[g][0] - m);
        float p1 = fast_exp2(s[g][1] - m);
        float p2 = fast_exp2(s[g][2] - m);
        float p3 = fast_exp2(s[g][3] - m);
        pk.u[half * 2] = (unsigned)bf16bits(p0) | ((unsigned)bf16bits(p1) << 16);
        pk.u[half * 2 + 1] = (unsigned)bf16bits(p2) | ((unsigned)bf16bits(p3) << 16);
      }
      pf[ks] = pk.v;
    }

    __syncthreads();  // QK done (K free), V_c staging drained

    // issue K_{c+1} staging (lands during PV)
    if (c + 1 < nch) stageK((c + 1) << 6);

    // PV + ones-column row-sum (pf in registers)
    __builtin_amdgcn_s_setprio(1);
#pragma unroll
    for (int ks = 0; ks < 2; ++ks) {
#pragma unroll
      for (int f = 0; f < 8; ++f) {
        unsigned row = (unsigned)(f * 16 + l16);
        short8 vf = *(const short8*)(Vl + row * 128u +
                                     (((unsigned)(ks * 64 + lhi * 16)) ^ swz_row(row)));
        o[f] = MFMA16x16(pf[ks], vf, o[f]);
      }
      lsum = MFMA16x16(pf[ks], onesf, lsum);
    }
    __builtin_amdgcn_s_setprio(0);

    __syncthreads();  // PV done (V free), K_{c+1} staging drained

    // issue V_{c+1} staging (lands during next QK+softmax)
    if (c + 1 < nch) stageV((c + 1) << 6);
  }

  // epilogue: O rows = q0w + lhi*4 + r, cols f*16 + l16
#pragma unroll
  for (int r = 0; r < 4; ++r) {
    float inv = 1.f / lsum[r];
    int row = q0w + lhi * 4 + r;
    size_t base = ((size_t)(b * 2048) + row) * 2048 + h * 128;
#pragma unroll
    for (int f = 0; f < 8; ++f)
      attnO[base + f * 16 + l16] = __float2bfloat16(o[f][r] * inv);
  }
}

// ---------------- launch ----------------
extern "C" void kernel_launch(void* const* d_in, const int* in_sizes, int n_in,
                              void* d_out, int out_size, void* d_ws, size_t ws_size,
                              hipStream_t stream) {
  const float* hs = (const float*)d_in[0];
  const float* cosT = (const float*)d_in[2];
  const float* sinT = (const float*)d_in[3];
  const float* Wq = (const float*)d_in[4];
  const float* Wk = (const float*)d_in[5];
  const float* Wv = (const float*)d_in[6];
  const float* Wo = (const float*)d_in[7];
  const float* qw = (const float*)d_in[8];
  const float* kw = (const float*)d_in[9];
  float* out = (float*)d_out;

  char* ws = (char*)d_ws;
  size_t off = 0;
  auto alloc = [&](size_t bytes) {
    char* p = ws + off;
    off += (bytes + 255) & ~(size_t)255;
    return p;
  };
  bf16_t* hsb  = (bf16_t*)alloc((size_t)4096 * 2048 * 2);
  bf16_t* wqkv = (bf16_t*)alloc((size_t)3072 * 2048 * 2);
  bf16_t* wot  = (bf16_t*)alloc((size_t)2048 * 2048 * 2);
  bf16_t* cqkv = (bf16_t*)alloc((size_t)4096 * 3072 * 2);  // QKV gemm out (bf16)
  bf16_t* qa   = (bf16_t*)alloc((size_t)2 * 16 * 2048 * 128 * 2);
  bf16_t* ka   = (bf16_t*)alloc((size_t)2 * 4 * 2048 * 128 * 2);
  bf16_t* vt   = (bf16_t*)alloc((size_t)2 * 4 * 2048 * 128 * 2);
  bf16_t* attn = (bf16_t*)cqkv;  // reuse (cqkv dead after relayout kernels)

  prep_kernel<<<18432, 256, 0, stream>>>(hs, hsb, Wq, Wk, Wv, Wo, wqkv, wot);
  gemm_bt_kernel<1><<<dim3(24, 32), 256, 0, stream>>>(hsb, wqkv, cqkv, 2048, 3072);
  post_kernel<<<22528, 256, 0, stream>>>(cqkv, cosT, sinT, qw, kw, qa, ka, vt);
  flash_kernel<<<1024, 256, 0, stream>>>(qa, ka, vt, attn);
  gemm_bt_kernel<0><<<dim3(16, 32), 256, 0, stream>>>(attn, wot, out, 2048, 2048);
}